// Round 4
// baseline (820.833 us; speedup 1.0000x reference)
//
#include <hip/hip_runtime.h>
#include <hip/hip_bf16.h>

#define N_NODES 50000
#define N_EDGES 800000
#define DIM 128
#define N_LAYERS 5
#define BN_EPS 1e-3f
#define NSLICE 4
#define SLICE_COLS 32
#define POOL_BLK_PER_SLICE 12500  // N_NODES / 4 waves per block

typedef __attribute__((ext_vector_type(8))) short bf16x8;
typedef __attribute__((ext_vector_type(4))) float f32x4;
typedef __attribute__((ext_vector_type(4))) unsigned int u32x4;
typedef __attribute__((ext_vector_type(2))) unsigned int u32x2;

__device__ __forceinline__ unsigned short f2bf(float f) {
    unsigned int v = __builtin_bit_cast(unsigned int, f);
    v += 0x7fffu + ((v >> 16) & 1u);
    return (unsigned short)(v >> 16);
}
__device__ __forceinline__ float bflo(unsigned int v) {
    return __builtin_bit_cast(float, v << 16);
}
__device__ __forceinline__ float bfhi(unsigned int v) {
    return __builtin_bit_cast(float, v & 0xffff0000u);
}

// ---- setup kernels -------------------------------------------------------

// copy x -> out chunk 0 (fp32) + hb0 (bf16 shadow, SLICED layout); zero cnt[]
// sliced layout: hb[slice][node][32 cols], slice s holds cols [32s, 32s+32)
__global__ void init_zero_kernel(const float* __restrict__ x, float* __restrict__ out,
                                 unsigned short* __restrict__ hb, int* __restrict__ cnt) {
    int t = blockIdx.x * blockDim.x + threadIdx.x;
    if (t < (N_NODES * DIM) / 4) {
        f32x4 v = ((const f32x4*)x)[t];
        __builtin_nontemporal_store(v, (f32x4*)out + t);
        unsigned short u[4] = {f2bf(v.x), f2bf(v.y), f2bf(v.z), f2bf(v.w)};
        int node = t >> 5;
        int c = (t & 31) * 4;            // col within the 128-wide row
        int sl = c >> 5;                 // slice
        int w = c & 31;                  // col within slice
        *(u32x2*)(hb + (size_t)sl * N_NODES * SLICE_COLS + (size_t)node * SLICE_COLS + w) =
            *(u32x2*)u;
    }
    int z = t - (N_NODES * DIM) / 4;
    if (z >= 0 && z < N_NODES) cnt[z] = 0;
}

__global__ void hist_kernel(const int* __restrict__ dst, int* __restrict__ cnt) {
    int e = blockIdx.x * blockDim.x + threadIdx.x;
    if (e < N_EDGES) atomicAdd(&cnt[dst[e]], 1);
}

// single-block exclusive scan of cnt[0..N_NODES) -> row_start, cursor
__global__ __launch_bounds__(1024) void scan_kernel(const int* __restrict__ cnt,
                                                    int* __restrict__ row_start,
                                                    int* __restrict__ cursor) {
    __shared__ int wsum[16];
    __shared__ int s_carry;
    const int tid = threadIdx.x;
    const int lane = tid & 63, wave = tid >> 6;
    if (tid == 0) s_carry = 0;
    __syncthreads();
    for (int base = 0; base < N_NODES; base += 4096) {
        int i0 = base + tid * 4;
        int v[4];
#pragma unroll
        for (int j = 0; j < 4; j++) {
            int i = i0 + j;
            v[j] = (i < N_NODES) ? cnt[i] : 0;
        }
        int s = v[0] + v[1] + v[2] + v[3];
        int x = s;
#pragma unroll
        for (int off = 1; off < 64; off <<= 1) {
            int t = __shfl_up(x, off, 64);
            if (lane >= off) x += t;
        }
        if (lane == 63) wsum[wave] = x;
        __syncthreads();
        if (wave == 0) {
            int w = (lane < 16) ? wsum[lane] : 0;
#pragma unroll
            for (int off = 1; off < 16; off <<= 1) {
                int t = __shfl_up(w, off, 64);
                if (lane >= off) w += t;
            }
            if (lane < 16) wsum[lane] = w;
        }
        __syncthreads();
        int waveoff = (wave > 0) ? wsum[wave - 1] : 0;
        int carry = s_carry;
        int run = carry + waveoff + (x - s);
#pragma unroll
        for (int j = 0; j < 4; j++) {
            int i = i0 + j;
            if (i < N_NODES) { row_start[i] = run; cursor[i] = run; }
            run += v[j];
        }
        __syncthreads();
        if (tid == 1023) s_carry = carry + wsum[15];
        __syncthreads();
    }
    if (tid == 0) row_start[N_NODES] = s_carry;
}

__global__ void fill_kernel(const int* __restrict__ src, const int* __restrict__ dst,
                            int* __restrict__ cursor, int* __restrict__ col) {
    int e = blockIdx.x * blockDim.x + threadIdx.x;
    if (e < N_EDGES) {
        int d = dst[e];
        int pos = atomicAdd(&cursor[d], 1);
        col[pos] = src[e];
    }
}

// pack W1/W2 (fp32->bf16) into B-fragment order + fold BN scale/shift
__global__ void prep_kernel(const float* __restrict__ W1, const float* __restrict__ W2,
                            unsigned short* __restrict__ wp,
                            const float* __restrict__ gamma, const float* __restrict__ beta,
                            const float* __restrict__ mean, const float* __restrict__ var,
                            float* __restrict__ scale, float* __restrict__ shift) {
    int t = blockIdx.x * blockDim.x + threadIdx.x;
    if (t < N_LAYERS * 2 * 2048) {
        int mat = t >> 11;
        int r = t & 2047;
        int ks = r >> 9, nt = (r >> 6) & 7, lane = r & 63;
        int layer = mat >> 1;
        const float* W = ((mat & 1) ? W2 : W1) + layer * DIM * DIM;
        int n = nt * 16 + (lane & 15);
        int kb = ks * 32 + (lane >> 4) * 8;
        unsigned short u[8];
#pragma unroll
        for (int j = 0; j < 8; j++) u[j] = f2bf(W[(kb + j) * DIM + n]);
        *(u32x4*)(wp + (size_t)mat * 16384 + ((ks * 8 + nt) * 64 + lane) * 8) = *(u32x4*)u;
    }
    int i = t - N_LAYERS * 2 * 2048;
    if (i >= 0 && i < N_LAYERS * DIM) {
        float sc = gamma[i] * rsqrtf(var[i] + BN_EPS);
        scale[i] = sc;
        shift[i] = beta[i] - mean[i] * sc;
    }
}

// ---- per-layer kernels ---------------------------------------------------

__device__ __forceinline__ void acc8(float* a, u32x4 v, float m) {
    a[0] = fmaf(m, bflo(v.x), a[0]); a[1] = fmaf(m, bfhi(v.x), a[1]);
    a[2] = fmaf(m, bflo(v.y), a[2]); a[3] = fmaf(m, bfhi(v.y), a[3]);
    a[4] = fmaf(m, bflo(v.z), a[4]); a[5] = fmaf(m, bfhi(v.z), a[5]);
    a[6] = fmaf(m, bflo(v.w), a[6]); a[7] = fmaf(m, bfhi(v.w), a[7]);
}

// L2-resident sliced pooling. One dispatch, slice-major block order: all
// concurrently-running blocks gather from the SAME 3.2MB column slice, which
// fits in every XCD's 4MiB L2 -> capacity misses to LLC eliminated.
// Lane map: group g = lane>>2 (16 edges per instruction), sub t = lane&3
// (4 lanes x 16B = one 64B slice-row). Avg-degree node = 1 gather instr/slice.
__global__ __launch_bounds__(256) void pool_kernel(const unsigned short* __restrict__ hbs,
                                                   const int* __restrict__ row_start,
                                                   const int* __restrict__ col,
                                                   const float* __restrict__ eps_l,
                                                   unsigned short* __restrict__ pooled_s) {
    const int wave = threadIdx.x >> 6, lane = threadIdx.x & 63;
    const int bid = blockIdx.x;
    const int slice = bid / POOL_BLK_PER_SLICE;
    const int nb = bid - slice * POOL_BLK_PER_SLICE;
    const int n = nb * 4 + wave;
    const unsigned short* tab = hbs + (size_t)slice * N_NODES * SLICE_COLS;
    const float ev = 1.0f + eps_l[0];
    const int s0 = row_start[n], s1 = row_start[n + 1];
    const int g = lane >> 2;   // which of 16 edges per instruction
    const int t = lane & 3;    // which 16B chunk of the 64B slice-row

    // self term (all lanes load same row -> coalesced broadcast; only g==0 keeps)
    u32x4 sv = *(const u32x4*)(tab + (size_t)n * SLICE_COLS + t * 8);
    float a[8] = {0.f, 0.f, 0.f, 0.f, 0.f, 0.f, 0.f, 0.f};
    acc8(a, sv, (g == 0) ? ev : 0.f);

    for (int base = s0; base < s1; base += 64) {
        const int rem = s1 - base;
        const int nn = rem < 64 ? rem : 64;
        int ci = (base + lane < s1) ? __builtin_nontemporal_load(&col[base + lane]) : 0;
        u32x4 v[4];
#pragma unroll
        for (int i = 0; i < 4; i++) {
            if (i * 16 < nn) {                      // wave-uniform skip
                int r = __shfl(ci, i * 16 + g, 64); // idx <= 63 always
                v[i] = *(const u32x4*)(tab + (size_t)r * SLICE_COLS + t * 8);
            }
        }
#pragma unroll
        for (int i = 0; i < 4; i++) {
            if (i * 16 < nn) {
                float m = (i * 16 + g < nn) ? 1.f : 0.f;  // tail-group mask
                acc8(a, v[i], m);
            }
        }
    }

    // combine 16 group-partials: xor-reduce over lanes 4,8,16,32
#pragma unroll
    for (int k = 0; k < 8; k++) {
        a[k] += __shfl_xor(a[k], 4, 64);
        a[k] += __shfl_xor(a[k], 8, 64);
        a[k] += __shfl_xor(a[k], 16, 64);
        a[k] += __shfl_xor(a[k], 32, 64);
    }
    if (g == 0) {
        unsigned short u[8];
#pragma unroll
        for (int k = 0; k < 8; k++) u[k] = f2bf(a[k]);
        __builtin_nontemporal_store(
            *(u32x4*)u,
            (u32x4*)(pooled_s + (size_t)slice * N_NODES * SLICE_COLS +
                     (size_t)n * SLICE_COLS + t * 8));
    }
}

// fused Linear1 -> ReLU -> Linear2 -> BN -> ReLU for a 64-row tile.
// A-fragments read from SLICED pooled (slice == ks); hb shadow written sliced.
__global__ __launch_bounds__(256) void mlp_kernel(
    const unsigned short* __restrict__ pooled_s,
    const unsigned short* __restrict__ wp1,
    const unsigned short* __restrict__ wp2,
    const float* __restrict__ b1,
    const float* __restrict__ b2,
    const float* __restrict__ bnscale,
    const float* __restrict__ bnshift,
    float* __restrict__ h_out,
    unsigned short* __restrict__ hb_out) {
    __shared__ __align__(16) unsigned short zfrag[4][4][64][8];  // z1 shuffle, wave-private
    const int tid = threadIdx.x;
    const int wave = tid >> 6, lane = tid & 63;
    const int m0 = blockIdx.x * 64;
    const int colc = lane & 15;
    const int quad = lane >> 4;
    const int arow = m0 + wave * 16 + colc;
    const int arow_c = arow < N_NODES ? arow : N_NODES - 1;

    bf16x8 a[4];
#pragma unroll
    for (int ks = 0; ks < 4; ks++)
        a[ks] = *(const bf16x8*)(pooled_s + (size_t)ks * N_NODES * SLICE_COLS +
                                 (size_t)arow_c * SLICE_COLS + quad * 8);

    f32x4 acc[8];
#pragma unroll
    for (int nt = 0; nt < 8; nt++) {
        acc[nt] = (f32x4){0.f, 0.f, 0.f, 0.f};
#pragma unroll
        for (int ks = 0; ks < 4; ks++) {
            bf16x8 b = *(const bf16x8*)(wp1 + ((ks * 8 + nt) * 64 + lane) * 8);
            acc[nt] = __builtin_amdgcn_mfma_f32_16x16x32_bf16(a[ks], b, acc[nt], 0, 0, 0);
        }
    }

    // bias + ReLU, write z1 to LDS in A-fragment layout (wave-private region)
#pragma unroll
    for (int nt = 0; nt < 8; nt++) {
        int n = nt * 16 + colc;
        float bias = b1[n];
#pragma unroll
        for (int r = 0; r < 4; r++) {
            float v = acc[nt][r] + bias;
            v = v > 0.f ? v : 0.f;
            int row16 = quad * 4 + r;
            zfrag[wave][n >> 5][(((n >> 3) & 3) << 4) | row16][n & 7] = f2bf(v);
        }
    }

#pragma unroll
    for (int ks = 0; ks < 4; ks++) a[ks] = *(const bf16x8*)(&zfrag[wave][ks][lane][0]);

    f32x4 acc2[8];
#pragma unroll
    for (int nt = 0; nt < 8; nt++) {
        acc2[nt] = (f32x4){0.f, 0.f, 0.f, 0.f};
#pragma unroll
        for (int ks = 0; ks < 4; ks++) {
            bf16x8 b = *(const bf16x8*)(wp2 + ((ks * 8 + nt) * 64 + lane) * 8);
            acc2[nt] = __builtin_amdgcn_mfma_f32_16x16x32_bf16(a[ks], b, acc2[nt], 0, 0, 0);
        }
    }

    // epilogue: +b2, BN, ReLU; nontemporal fp32 out + sliced bf16 shadow
#pragma unroll
    for (int nt = 0; nt < 8; nt++) {
        int n = nt * 16 + colc;
        float bias = b2[n];
        float sc = bnscale[n], sh = bnshift[n];
        unsigned short* hslice = hb_out + (size_t)(n >> 5) * N_NODES * SLICE_COLS;
        int w = n & 31;
#pragma unroll
        for (int r = 0; r < 4; r++) {
            int row = m0 + wave * 16 + quad * 4 + r;
            if (row < N_NODES) {
                float z = acc2[nt][r] + bias;
                z = z * sc + sh;
                z = z > 0.f ? z : 0.f;
                __builtin_nontemporal_store(z, &h_out[row * DIM + n]);
                hslice[(size_t)row * SLICE_COLS + w] = f2bf(z);
            }
        }
    }
}

// ---- launch --------------------------------------------------------------

extern "C" void kernel_launch(void* const* d_in, const int* in_sizes, int n_in,
                              void* d_out, int out_size, void* d_ws, size_t ws_size,
                              hipStream_t stream) {
    const float* x     = (const float*)d_in[0];
    const int* esrc    = (const int*)d_in[1];
    const int* edst    = (const int*)d_in[2];
    const float* eps   = (const float*)d_in[3];
    const float* W1    = (const float*)d_in[4];
    const float* b1    = (const float*)d_in[5];
    const float* W2    = (const float*)d_in[6];
    const float* b2    = (const float*)d_in[7];
    const float* gam   = (const float*)d_in[8];
    const float* bet   = (const float*)d_in[9];
    const float* bmean = (const float*)d_in[10];
    const float* bvar  = (const float*)d_in[11];
    float* out = (float*)d_out;

    char* ws = (char*)d_ws;
    unsigned short* hb0   = (unsigned short*)(ws);               // 12,800,000 B (sliced)
    unsigned short* hb1   = (unsigned short*)(ws + 12800000);    // 12,800,000 B (sliced)
    int*   col        = (int*)  (ws + 25600000);                 //  3,200,000 B
    int*   row_start  = (int*)  (ws + 28800000);                 //    200,004 B
    int*   cursor     = (int*)  (ws + 29000192);                 //    200,000 B
    int*   cnt        = (int*)  (ws + 29200384);                 //    200,000 B
    unsigned short* wpack = (unsigned short*)(ws + 29400576);    //    327,680 B
    float* bnscale    = (float*)(ws + 29728256);                 //      2,560 B
    float* bnshift    = (float*)(ws + 29730816);                 //      2,560 B
    unsigned short* pooled_s = (unsigned short*)(ws + 29733376); // 12,800,000 B (sliced)

    init_zero_kernel<<<((N_NODES * DIM) / 4 + N_NODES + 255) / 256, 256, 0, stream>>>(
        x, out, hb0, cnt);
    hist_kernel<<<(N_EDGES + 255) / 256, 256, 0, stream>>>(edst, cnt);
    scan_kernel<<<1, 1024, 0, stream>>>(cnt, row_start, cursor);
    fill_kernel<<<(N_EDGES + 255) / 256, 256, 0, stream>>>(esrc, edst, cursor, col);
    prep_kernel<<<(N_LAYERS * 2 * 2048 + N_LAYERS * DIM + 255) / 256, 256, 0, stream>>>(
        W1, W2, wpack, gam, bet, bmean, bvar, bnscale, bnshift);

    const int pool_blocks = NSLICE * POOL_BLK_PER_SLICE;  // 50000, slice-major
    const int mlp_blocks  = (N_NODES + 63) / 64;          // 782
    unsigned short* hbuf[2] = {hb0, hb1};
    for (int l = 0; l < N_LAYERS; l++) {
        float* h_next = out + (size_t)(l + 1) * N_NODES * DIM;
        pool_kernel<<<pool_blocks, 256, 0, stream>>>(hbuf[l & 1], row_start, col, eps + l,
                                                     pooled_s);
        mlp_kernel<<<mlp_blocks, 256, 0, stream>>>(
            pooled_s,
            wpack + (size_t)(l * 2) * 16384,
            wpack + (size_t)(l * 2 + 1) * 16384,
            b1 + l * DIM, b2 + l * DIM,
            bnscale + l * DIM, bnshift + l * DIM,
            h_next, hbuf[(l + 1) & 1]);
    }
}

// Round 5
// 743.968 us; speedup vs baseline: 1.1033x; 1.1033x over previous
//
#include <hip/hip_runtime.h>
#include <hip/hip_bf16.h>

#define N_NODES 50000
#define N_EDGES 800000
#define DIM 128
#define N_LAYERS 5
#define BN_EPS 1e-3f
#define CMPAD 16  // floats per column slot (64B padding to spread atomics)

typedef __attribute__((ext_vector_type(8))) short bf16x8;
typedef __attribute__((ext_vector_type(4))) float f32x4;
typedef __attribute__((ext_vector_type(4))) unsigned int u32x4;
typedef __attribute__((ext_vector_type(2))) unsigned int u32x2;

__device__ __forceinline__ unsigned short f2bf(float f) {
    unsigned int v = __builtin_bit_cast(unsigned int, f);
    v += 0x7fffu + ((v >> 16) & 1u);
    return (unsigned short)(v >> 16);
}
__device__ __forceinline__ float bflo(unsigned int v) {
    return __builtin_bit_cast(float, v << 16);
}
__device__ __forceinline__ float bfhi(unsigned int v) {
    return __builtin_bit_cast(float, v & 0xffff0000u);
}

// ---- setup kernels -------------------------------------------------------

// copy x -> out chunk 0 (fp32) + hb (bf16 shadow, row-major); zero cnt + cmax
__global__ void init_zero_kernel(const float* __restrict__ x, float* __restrict__ out,
                                 unsigned short* __restrict__ hb, int* __restrict__ cnt,
                                 unsigned int* __restrict__ cmax) {
    int t = blockIdx.x * blockDim.x + threadIdx.x;
    if (t < (N_NODES * DIM) / 4) {
        f32x4 v = ((const f32x4*)x)[t];
        __builtin_nontemporal_store(v, (f32x4*)out + t);
        unsigned short u[4] = {f2bf(v.x), f2bf(v.y), f2bf(v.z), f2bf(v.w)};
        *(u32x2*)(hb + t * 4) = *(u32x2*)u;
    }
    int z = t - (N_NODES * DIM) / 4;
    if (z >= 0 && z < N_NODES) cnt[z] = 0;
    int z2 = z - N_NODES;
    if (z2 >= 0 && z2 < 2 * DIM * CMPAD) cmax[z2] = 0;
}

// per-column absmax of hb (bf16) -> cmax slot 0 (float bits, values >= 0)
__global__ __launch_bounds__(256) void colmax0_kernel(const unsigned short* __restrict__ hb,
                                                      unsigned int* __restrict__ cmax) {
    __shared__ unsigned int cm[DIM];
    const int tid = threadIdx.x;
    if (tid < DIM) cm[tid] = 0;
    __syncthreads();
    const int total = N_NODES * DIM / 8;     // 16B chunks
    const int stride = gridDim.x * blockDim.x;  // 65536, %16==0 -> col phase invariant
    float m[8] = {0.f, 0.f, 0.f, 0.f, 0.f, 0.f, 0.f, 0.f};
    for (int e = blockIdx.x * blockDim.x + tid; e < total; e += stride) {
        u32x4 v = *(const u32x4*)(hb + (size_t)e * 8);
        m[0] = fmaxf(m[0], fabsf(bflo(v.x))); m[1] = fmaxf(m[1], fabsf(bfhi(v.x)));
        m[2] = fmaxf(m[2], fabsf(bflo(v.y))); m[3] = fmaxf(m[3], fabsf(bfhi(v.y)));
        m[4] = fmaxf(m[4], fabsf(bflo(v.z))); m[5] = fmaxf(m[5], fabsf(bfhi(v.z)));
        m[6] = fmaxf(m[6], fabsf(bflo(v.w))); m[7] = fmaxf(m[7], fabsf(bfhi(v.w)));
    }
    const int cb = (tid & 15) * 8;
#pragma unroll
    for (int k = 0; k < 8; k++)
        atomicMax(&cm[cb + k], __builtin_bit_cast(unsigned int, m[k]));
    __syncthreads();
    if (tid < DIM) atomicMax(&cmax[tid * CMPAD], cm[tid]);
}

__global__ void hist_kernel(const int* __restrict__ dst, int* __restrict__ cnt) {
    int e = blockIdx.x * blockDim.x + threadIdx.x;
    if (e < N_EDGES) atomicAdd(&cnt[dst[e]], 1);
}

// single-block exclusive scan of cnt[0..N_NODES) -> row_start, cursor
__global__ __launch_bounds__(1024) void scan_kernel(const int* __restrict__ cnt,
                                                    int* __restrict__ row_start,
                                                    int* __restrict__ cursor) {
    __shared__ int wsum[16];
    __shared__ int s_carry;
    const int tid = threadIdx.x;
    const int lane = tid & 63, wave = tid >> 6;
    if (tid == 0) s_carry = 0;
    __syncthreads();
    for (int base = 0; base < N_NODES; base += 4096) {
        int i0 = base + tid * 4;
        int v[4];
#pragma unroll
        for (int j = 0; j < 4; j++) {
            int i = i0 + j;
            v[j] = (i < N_NODES) ? cnt[i] : 0;
        }
        int s = v[0] + v[1] + v[2] + v[3];
        int x = s;
#pragma unroll
        for (int off = 1; off < 64; off <<= 1) {
            int t = __shfl_up(x, off, 64);
            if (lane >= off) x += t;
        }
        if (lane == 63) wsum[wave] = x;
        __syncthreads();
        if (wave == 0) {
            int w = (lane < 16) ? wsum[lane] : 0;
#pragma unroll
            for (int off = 1; off < 16; off <<= 1) {
                int t = __shfl_up(w, off, 64);
                if (lane >= off) w += t;
            }
            if (lane < 16) wsum[lane] = w;
        }
        __syncthreads();
        int waveoff = (wave > 0) ? wsum[wave - 1] : 0;
        int carry = s_carry;
        int run = carry + waveoff + (x - s);
#pragma unroll
        for (int j = 0; j < 4; j++) {
            int i = i0 + j;
            if (i < N_NODES) { row_start[i] = run; cursor[i] = run; }
            run += v[j];
        }
        __syncthreads();
        if (tid == 1023) s_carry = carry + wsum[15];
        __syncthreads();
    }
    if (tid == 0) row_start[N_NODES] = s_carry;
}

__global__ void fill_kernel(const int* __restrict__ src, const int* __restrict__ dst,
                            int* __restrict__ cursor, int* __restrict__ col) {
    int e = blockIdx.x * blockDim.x + threadIdx.x;
    if (e < N_EDGES) {
        int d = dst[e];
        int pos = atomicAdd(&cursor[d], 1);
        col[pos] = src[e];
    }
}

// pack W1/W2 (fp32->bf16) into B-fragment order + fold BN scale/shift
__global__ void prep_kernel(const float* __restrict__ W1, const float* __restrict__ W2,
                            unsigned short* __restrict__ wp,
                            const float* __restrict__ gamma, const float* __restrict__ beta,
                            const float* __restrict__ mean, const float* __restrict__ var,
                            float* __restrict__ scale, float* __restrict__ shift) {
    int t = blockIdx.x * blockDim.x + threadIdx.x;
    if (t < N_LAYERS * 2 * 2048) {
        int mat = t >> 11;
        int r = t & 2047;
        int ks = r >> 9, nt = (r >> 6) & 7, lane = r & 63;
        int layer = mat >> 1;
        const float* W = ((mat & 1) ? W2 : W1) + layer * DIM * DIM;
        int n = nt * 16 + (lane & 15);
        int kb = ks * 32 + (lane >> 4) * 8;
        unsigned short u[8];
#pragma unroll
        for (int j = 0; j < 8; j++) u[j] = f2bf(W[(kb + j) * DIM + n]);
        *(u32x4*)(wp + (size_t)mat * 16384 + ((ks * 8 + nt) * 64 + lane) * 8) = *(u32x4*)u;
    }
    int i = t - N_LAYERS * 2 * 2048;
    if (i >= 0 && i < N_LAYERS * DIM) {
        float sc = gamma[i] * rsqrtf(var[i] + BN_EPS);
        scale[i] = sc;
        shift[i] = beta[i] - mean[i] * sc;
    }
}

// ---- per-layer kernels ---------------------------------------------------

// quantize hb (bf16, row-major) -> q8 int8 with per-column scale 127/cmax.
// Also zeroes the NEXT cmax slot (consumed by this layer's mlp).
__global__ __launch_bounds__(256) void quant_kernel(const unsigned short* __restrict__ hb,
                                                    const unsigned int* __restrict__ cmax_cur,
                                                    unsigned int* __restrict__ cmax_next,
                                                    signed char* __restrict__ q8) {
    const int tid = blockIdx.x * blockDim.x + threadIdx.x;  // one 8-col chunk per thread
    if (blockIdx.x == 0 && threadIdx.x < DIM) cmax_next[threadIdx.x * CMPAD] = 0;
    const int cb = (tid & 15) * 8;
    float inv[8];
#pragma unroll
    for (int k = 0; k < 8; k++) {
        float mx = __builtin_bit_cast(float, cmax_cur[(cb + k) * CMPAD]);
        inv[k] = mx > 0.f ? 127.0f / mx : 0.f;
    }
    u32x4 v = *(const u32x4*)(hb + (size_t)tid * 8);
    float f[8] = {bflo(v.x), bfhi(v.x), bflo(v.y), bfhi(v.y),
                  bflo(v.z), bfhi(v.z), bflo(v.w), bfhi(v.w)};
    unsigned int b[8];
#pragma unroll
    for (int k = 0; k < 8; k++) {
        int q = (int)rintf(f[k] * inv[k]);
        q = q > 127 ? 127 : (q < -127 ? -127 : q);  // guard bf16-vs-f32 max skew
        b[k] = (unsigned int)q & 255u;
    }
    u32x2 o;
    o.x = b[0] | (b[1] << 8) | (b[2] << 16) | (b[3] << 24);
    o.y = b[4] | (b[5] << 8) | (b[6] << 16) | (b[7] << 24);
    __builtin_nontemporal_store(o, (u32x2*)(q8 + (size_t)tid * 8));
}

__device__ __forceinline__ void accq(int* a, unsigned int w, int k) {
    a[k + 0] += (int)(w << 24) >> 24;
    a[k + 1] += (int)(w << 16) >> 24;
    a[k + 2] += (int)(w << 8) >> 24;
    a[k + 3] += (int)w >> 24;
}

// int8 gather pooling: one wave per node. Row = 128B = one cache line.
// 8 lanes x 16B per row -> 8 edges per gather instruction; int32 accumulate;
// shfl_xor reduce over the 8 groups; dequant by per-column scale; self in bf16.
__global__ __launch_bounds__(256) void pool_kernel(const signed char* __restrict__ q8,
                                                   const unsigned short* __restrict__ hb,
                                                   const int* __restrict__ row_start,
                                                   const int* __restrict__ col,
                                                   const float* __restrict__ eps_l,
                                                   const unsigned int* __restrict__ cmax,
                                                   unsigned short* __restrict__ pooled_b) {
    const int wave = threadIdx.x >> 6, lane = threadIdx.x & 63;
    const int n = __builtin_amdgcn_readfirstlane(blockIdx.x * 4 + wave);
    const int s0 = row_start[n], s1 = row_start[n + 1];
    const int g = lane >> 3;   // which of 8 edges per instruction
    const int t = lane & 7;    // which 16B chunk of the 128B row

    int acc[16] = {0, 0, 0, 0, 0, 0, 0, 0, 0, 0, 0, 0, 0, 0, 0, 0};

    for (int base = s0; base < s1; base += 64) {
        const int rem = s1 - base;
        const int nn = rem < 64 ? rem : 64;
        int ci = (base + lane < s1) ? __builtin_nontemporal_load(&col[base + lane]) : 0;
        for (int j = 0; j < nn; j += 24) {
            u32x4 v[3];
#pragma unroll
            for (int i = 0; i < 3; i++) {
                int start = j + i * 8;
                if (start < nn) {                       // wave-uniform skip
                    int r = __shfl(ci, start + g, 64);  // start+g <= 63 always
                    u32x4 tmp = *(const u32x4*)(q8 + (size_t)r * DIM + t * 16);
                    u32x4 zero = {0u, 0u, 0u, 0u};
                    v[i] = (start + g < nn) ? tmp : zero;  // tail-group mask
                }
            }
#pragma unroll
            for (int i = 0; i < 3; i++) {
                if (j + i * 8 < nn) {
                    accq(acc, v[i].x, 0);
                    accq(acc, v[i].y, 4);
                    accq(acc, v[i].z, 8);
                    accq(acc, v[i].w, 12);
                }
            }
        }
    }

    // combine the 8 group-partials (g spans lane bits 3..5)
#pragma unroll
    for (int k = 0; k < 16; k++) {
        acc[k] += __shfl_xor(acc[k], 8, 64);
        acc[k] += __shfl_xor(acc[k], 16, 64);
        acc[k] += __shfl_xor(acc[k], 32, 64);
    }
    if (g == 0) {
        const float ev = 1.0f + eps_l[0];
        // self row (bf16): cols t*16 .. t*16+15
        u32x4 sa = *(const u32x4*)(hb + (size_t)n * DIM + t * 16);
        u32x4 sb = *(const u32x4*)(hb + (size_t)n * DIM + t * 16 + 8);
        float self[16] = {bflo(sa.x), bfhi(sa.x), bflo(sa.y), bfhi(sa.y),
                          bflo(sa.z), bfhi(sa.z), bflo(sa.w), bfhi(sa.w),
                          bflo(sb.x), bfhi(sb.x), bflo(sb.y), bfhi(sb.y),
                          bflo(sb.z), bfhi(sb.z), bflo(sb.w), bfhi(sb.w)};
        unsigned short u[16];
#pragma unroll
        for (int k = 0; k < 16; k++) {
            float s = __builtin_bit_cast(float, cmax[(t * 16 + k) * CMPAD]) * (1.0f / 127.0f);
            u[k] = f2bf((float)acc[k] * s + ev * self[k]);
        }
        __builtin_nontemporal_store(*(u32x4*)u,
                                    (u32x4*)(pooled_b + (size_t)n * DIM + t * 16));
        __builtin_nontemporal_store(*(u32x4*)(u + 8),
                                    (u32x4*)(pooled_b + (size_t)n * DIM + t * 16 + 8));
    }
}

// fused Linear1 -> ReLU -> Linear2 -> BN -> ReLU for a 64-row tile.
// Also produces per-column max of the output (for next layer's quantization).
__global__ __launch_bounds__(256) void mlp_kernel(
    const unsigned short* __restrict__ pooled_b,
    const unsigned short* __restrict__ wp1,
    const unsigned short* __restrict__ wp2,
    const float* __restrict__ b1,
    const float* __restrict__ b2,
    const float* __restrict__ bnscale,
    const float* __restrict__ bnshift,
    float* __restrict__ h_out,
    unsigned short* __restrict__ hb_out,
    unsigned int* __restrict__ cmax_next) {
    __shared__ __align__(16) unsigned short zfrag[4][4][64][8];  // z1 shuffle, wave-private
    __shared__ unsigned int cmg[DIM];
    const int tid = threadIdx.x;
    const int wave = tid >> 6, lane = tid & 63;
    const int m0 = blockIdx.x * 64;
    const int colc = lane & 15;
    const int quad = lane >> 4;
    const int arow = m0 + wave * 16 + colc;
    const int arow_c = arow < N_NODES ? arow : N_NODES - 1;
    if (tid < DIM) cmg[tid] = 0;

    bf16x8 a[4];
#pragma unroll
    for (int ks = 0; ks < 4; ks++)
        a[ks] = *(const bf16x8*)(pooled_b + arow_c * DIM + ks * 32 + quad * 8);

    f32x4 acc[8];
#pragma unroll
    for (int nt = 0; nt < 8; nt++) {
        acc[nt] = (f32x4){0.f, 0.f, 0.f, 0.f};
#pragma unroll
        for (int ks = 0; ks < 4; ks++) {
            bf16x8 b = *(const bf16x8*)(wp1 + ((ks * 8 + nt) * 64 + lane) * 8);
            acc[nt] = __builtin_amdgcn_mfma_f32_16x16x32_bf16(a[ks], b, acc[nt], 0, 0, 0);
        }
    }

    // bias + ReLU, write z1 to LDS in A-fragment layout (wave-private region)
#pragma unroll
    for (int nt = 0; nt < 8; nt++) {
        int n = nt * 16 + colc;
        float bias = b1[n];
#pragma unroll
        for (int r = 0; r < 4; r++) {
            float v = acc[nt][r] + bias;
            v = v > 0.f ? v : 0.f;
            int row16 = quad * 4 + r;
            zfrag[wave][n >> 5][(((n >> 3) & 3) << 4) | row16][n & 7] = f2bf(v);
        }
    }

#pragma unroll
    for (int ks = 0; ks < 4; ks++) a[ks] = *(const bf16x8*)(&zfrag[wave][ks][lane][0]);

    f32x4 acc2[8];
#pragma unroll
    for (int nt = 0; nt < 8; nt++) {
        acc2[nt] = (f32x4){0.f, 0.f, 0.f, 0.f};
#pragma unroll
        for (int ks = 0; ks < 4; ks++) {
            bf16x8 b = *(const bf16x8*)(wp2 + ((ks * 8 + nt) * 64 + lane) * 8);
            acc2[nt] = __builtin_amdgcn_mfma_f32_16x16x32_bf16(a[ks], b, acc2[nt], 0, 0, 0);
        }
    }

    // epilogue: +b2, BN, ReLU; fp32 out + bf16 shadow; track per-column max
    float cmx[8];
#pragma unroll
    for (int nt = 0; nt < 8; nt++) {
        int n = nt * 16 + colc;
        float bias = b2[n];
        float sc = bnscale[n], sh = bnshift[n];
        cmx[nt] = 0.f;
#pragma unroll
        for (int r = 0; r < 4; r++) {
            int row = m0 + wave * 16 + quad * 4 + r;
            if (row < N_NODES) {
                float z = acc2[nt][r] + bias;
                z = z * sc + sh;
                z = z > 0.f ? z : 0.f;
                __builtin_nontemporal_store(z, &h_out[row * DIM + n]);
                hb_out[row * DIM + n] = f2bf(z);
                cmx[nt] = fmaxf(cmx[nt], z);
            }
        }
    }
    __syncthreads();  // cmg zero-init visible
#pragma unroll
    for (int nt = 0; nt < 8; nt++)
        atomicMax(&cmg[nt * 16 + colc], __builtin_bit_cast(unsigned int, cmx[nt]));
    __syncthreads();
    if (tid < DIM) atomicMax(&cmax_next[tid * CMPAD], cmg[tid]);
}

// ---- launch --------------------------------------------------------------

extern "C" void kernel_launch(void* const* d_in, const int* in_sizes, int n_in,
                              void* d_out, int out_size, void* d_ws, size_t ws_size,
                              hipStream_t stream) {
    const float* x     = (const float*)d_in[0];
    const int* esrc    = (const int*)d_in[1];
    const int* edst    = (const int*)d_in[2];
    const float* eps   = (const float*)d_in[3];
    const float* W1    = (const float*)d_in[4];
    const float* b1    = (const float*)d_in[5];
    const float* W2    = (const float*)d_in[6];
    const float* b2    = (const float*)d_in[7];
    const float* gam   = (const float*)d_in[8];
    const float* bet   = (const float*)d_in[9];
    const float* bmean = (const float*)d_in[10];
    const float* bvar  = (const float*)d_in[11];
    float* out = (float*)d_out;

    char* ws = (char*)d_ws;
    unsigned short* hb  = (unsigned short*)(ws);                // 12,800,000 B
    int*   col        = (int*)  (ws + 12800000);                //  3,200,000 B
    int*   row_start  = (int*)  (ws + 16000000);                //    200,004 B
    int*   cursor     = (int*)  (ws + 16200192);                //    200,000 B
    int*   cnt        = (int*)  (ws + 16400384);                //    200,000 B
    unsigned short* wpack = (unsigned short*)(ws + 16600576);   //    327,680 B
    float* bnscale    = (float*)(ws + 16928256);                //      2,560 B
    float* bnshift    = (float*)(ws + 16930816);                //      2,560 B
    unsigned int* cmax = (unsigned int*)(ws + 16933376);        //     16,384 B (2 slots)
    signed char* q8   = (signed char*)(ws + 16949760);          //  6,400,000 B
    unsigned short* pooled_b = (unsigned short*)(ws + 23349760); // 12,800,000 B

    init_zero_kernel<<<(1600000 + N_NODES + 2 * DIM * CMPAD + 255) / 256, 256, 0, stream>>>(
        x, out, hb, cnt, cmax);
    colmax0_kernel<<<256, 256, 0, stream>>>(hb, cmax);
    hist_kernel<<<(N_EDGES + 255) / 256, 256, 0, stream>>>(edst, cnt);
    scan_kernel<<<1, 1024, 0, stream>>>(cnt, row_start, cursor);
    fill_kernel<<<(N_EDGES + 255) / 256, 256, 0, stream>>>(esrc, edst, cursor, col);
    prep_kernel<<<(N_LAYERS * 2 * 2048 + N_LAYERS * DIM + 255) / 256, 256, 0, stream>>>(
        W1, W2, wpack, gam, bet, bmean, bvar, bnscale, bnshift);

    const int quant_blocks = (N_NODES * DIM / 8) / 256;  // 3125
    const int pool_blocks  = N_NODES / 4;                // 12500
    const int mlp_blocks   = (N_NODES + 63) / 64;        // 782
    for (int l = 0; l < N_LAYERS; l++) {
        float* h_next = out + (size_t)(l + 1) * N_NODES * DIM;
        unsigned int* cm_cur  = cmax + (size_t)(l & 1) * DIM * CMPAD;
        unsigned int* cm_next = cmax + (size_t)((l + 1) & 1) * DIM * CMPAD;
        quant_kernel<<<quant_blocks, 256, 0, stream>>>(hb, cm_cur, cm_next, q8);
        pool_kernel<<<pool_blocks, 256, 0, stream>>>(q8, hb, row_start, col, eps + l,
                                                     cm_cur, pooled_b);
        mlp_kernel<<<mlp_blocks, 256, 0, stream>>>(
            pooled_b,
            wpack + (size_t)(l * 2) * 16384,
            wpack + (size_t)(l * 2 + 1) * 16384,
            b1 + l * DIM, b2 + l * DIM,
            bnscale + l * DIM, bnshift + l * DIM,
            h_next, hb, cm_next);
    }
}

// Round 6
// 713.165 us; speedup vs baseline: 1.1510x; 1.0432x over previous
//
#include <hip/hip_runtime.h>
#include <hip/hip_bf16.h>

#define N_NODES 50000
#define N_EDGES 800000
#define DIM 128
#define N_LAYERS 5
#define BN_EPS 1e-3f
#define CMPAD 16  // floats per column slot (64B padding to spread atomics)

typedef __attribute__((ext_vector_type(8))) short bf16x8;
typedef __attribute__((ext_vector_type(4))) float f32x4;
typedef __attribute__((ext_vector_type(4))) unsigned int u32x4;
typedef __attribute__((ext_vector_type(2))) unsigned int u32x2;

__device__ __forceinline__ unsigned short f2bf(float f) {
    unsigned int v = __builtin_bit_cast(unsigned int, f);
    v += 0x7fffu + ((v >> 16) & 1u);
    return (unsigned short)(v >> 16);
}
__device__ __forceinline__ float bflo(unsigned int v) {
    return __builtin_bit_cast(float, v << 16);
}
__device__ __forceinline__ float bfhi(unsigned int v) {
    return __builtin_bit_cast(float, v & 0xffff0000u);
}

// ---- setup kernels -------------------------------------------------------

// copy x -> out chunk 0 (fp32) + hb (bf16 shadow, row-major); zero cnt + cmax
__global__ void init_zero_kernel(const float* __restrict__ x, float* __restrict__ out,
                                 unsigned short* __restrict__ hb, int* __restrict__ cnt,
                                 unsigned int* __restrict__ cmax) {
    int t = blockIdx.x * blockDim.x + threadIdx.x;
    if (t < (N_NODES * DIM) / 4) {
        f32x4 v = ((const f32x4*)x)[t];
        __builtin_nontemporal_store(v, (f32x4*)out + t);
        unsigned short u[4] = {f2bf(v.x), f2bf(v.y), f2bf(v.z), f2bf(v.w)};
        *(u32x2*)(hb + t * 4) = *(u32x2*)u;
    }
    int z = t - (N_NODES * DIM) / 4;
    if (z >= 0 && z < N_NODES) cnt[z] = 0;
    int z2 = z - N_NODES;
    if (z2 >= 0 && z2 < 2 * DIM * CMPAD) cmax[z2] = 0;
}

// per-column absmax of hb (bf16) -> cmax slot 0 (float bits, values >= 0)
__global__ __launch_bounds__(256) void colmax0_kernel(const unsigned short* __restrict__ hb,
                                                      unsigned int* __restrict__ cmax) {
    __shared__ unsigned int cm[DIM];
    const int tid = threadIdx.x;
    if (tid < DIM) cm[tid] = 0;
    __syncthreads();
    const int total = N_NODES * DIM / 8;     // 16B chunks
    const int stride = gridDim.x * blockDim.x;  // 65536, %16==0 -> col phase invariant
    float m[8] = {0.f, 0.f, 0.f, 0.f, 0.f, 0.f, 0.f, 0.f};
    for (int e = blockIdx.x * blockDim.x + tid; e < total; e += stride) {
        u32x4 v = *(const u32x4*)(hb + (size_t)e * 8);
        m[0] = fmaxf(m[0], fabsf(bflo(v.x))); m[1] = fmaxf(m[1], fabsf(bfhi(v.x)));
        m[2] = fmaxf(m[2], fabsf(bflo(v.y))); m[3] = fmaxf(m[3], fabsf(bfhi(v.y)));
        m[4] = fmaxf(m[4], fabsf(bflo(v.z))); m[5] = fmaxf(m[5], fabsf(bfhi(v.z)));
        m[6] = fmaxf(m[6], fabsf(bflo(v.w))); m[7] = fmaxf(m[7], fabsf(bfhi(v.w)));
    }
    const int cb = (tid & 15) * 8;
#pragma unroll
    for (int k = 0; k < 8; k++)
        atomicMax(&cm[cb + k], __builtin_bit_cast(unsigned int, m[k]));
    __syncthreads();
    if (tid < DIM) atomicMax(&cmax[tid * CMPAD], cm[tid]);
}

__global__ void hist_kernel(const int* __restrict__ dst, int* __restrict__ cnt) {
    int e = blockIdx.x * blockDim.x + threadIdx.x;
    if (e < N_EDGES) atomicAdd(&cnt[dst[e]], 1);
}

// single-block exclusive scan of cnt[0..N_NODES) -> row_start, cursor
__global__ __launch_bounds__(1024) void scan_kernel(const int* __restrict__ cnt,
                                                    int* __restrict__ row_start,
                                                    int* __restrict__ cursor) {
    __shared__ int wsum[16];
    __shared__ int s_carry;
    const int tid = threadIdx.x;
    const int lane = tid & 63, wave = tid >> 6;
    if (tid == 0) s_carry = 0;
    __syncthreads();
    for (int base = 0; base < N_NODES; base += 4096) {
        int i0 = base + tid * 4;
        int v[4];
#pragma unroll
        for (int j = 0; j < 4; j++) {
            int i = i0 + j;
            v[j] = (i < N_NODES) ? cnt[i] : 0;
        }
        int s = v[0] + v[1] + v[2] + v[3];
        int x = s;
#pragma unroll
        for (int off = 1; off < 64; off <<= 1) {
            int t = __shfl_up(x, off, 64);
            if (lane >= off) x += t;
        }
        if (lane == 63) wsum[wave] = x;
        __syncthreads();
        if (wave == 0) {
            int w = (lane < 16) ? wsum[lane] : 0;
#pragma unroll
            for (int off = 1; off < 16; off <<= 1) {
                int t = __shfl_up(w, off, 64);
                if (lane >= off) w += t;
            }
            if (lane < 16) wsum[lane] = w;
        }
        __syncthreads();
        int waveoff = (wave > 0) ? wsum[wave - 1] : 0;
        int carry = s_carry;
        int run = carry + waveoff + (x - s);
#pragma unroll
        for (int j = 0; j < 4; j++) {
            int i = i0 + j;
            if (i < N_NODES) { row_start[i] = run; cursor[i] = run; }
            run += v[j];
        }
        __syncthreads();
        if (tid == 1023) s_carry = carry + wsum[15];
        __syncthreads();
    }
    if (tid == 0) row_start[N_NODES] = s_carry;
}

__global__ void fill_kernel(const int* __restrict__ src, const int* __restrict__ dst,
                            int* __restrict__ cursor, int* __restrict__ col) {
    int e = blockIdx.x * blockDim.x + threadIdx.x;
    if (e < N_EDGES) {
        int d = dst[e];
        int pos = atomicAdd(&cursor[d], 1);
        col[pos] = src[e];
    }
}

// pack W1/W2 (fp32->bf16) into B-fragment order + fold BN scale/shift
__global__ void prep_kernel(const float* __restrict__ W1, const float* __restrict__ W2,
                            unsigned short* __restrict__ wp,
                            const float* __restrict__ gamma, const float* __restrict__ beta,
                            const float* __restrict__ mean, const float* __restrict__ var,
                            float* __restrict__ scale, float* __restrict__ shift) {
    int t = blockIdx.x * blockDim.x + threadIdx.x;
    if (t < N_LAYERS * 2 * 2048) {
        int mat = t >> 11;
        int r = t & 2047;
        int ks = r >> 9, nt = (r >> 6) & 7, lane = r & 63;
        int layer = mat >> 1;
        const float* W = ((mat & 1) ? W2 : W1) + layer * DIM * DIM;
        int n = nt * 16 + (lane & 15);
        int kb = ks * 32 + (lane >> 4) * 8;
        unsigned short u[8];
#pragma unroll
        for (int j = 0; j < 8; j++) u[j] = f2bf(W[(kb + j) * DIM + n]);
        *(u32x4*)(wp + (size_t)mat * 16384 + ((ks * 8 + nt) * 64 + lane) * 8) = *(u32x4*)u;
    }
    int i = t - N_LAYERS * 2 * 2048;
    if (i >= 0 && i < N_LAYERS * DIM) {
        float sc = gamma[i] * rsqrtf(var[i] + BN_EPS);
        scale[i] = sc;
        shift[i] = beta[i] - mean[i] * sc;
    }
}

// ---- per-layer kernels ---------------------------------------------------

// quantize hb (bf16, row-major) -> q8 int8 with per-column scale 127/cmax.
// Block 0 also zeroes the NEXT cmax slot and emits the compact dequant
// scale array sc128[c] = cmax[c]/127 (pool reads it coalesced).
__global__ __launch_bounds__(256) void quant_kernel(const unsigned short* __restrict__ hb,
                                                    const unsigned int* __restrict__ cmax_cur,
                                                    unsigned int* __restrict__ cmax_next,
                                                    float* __restrict__ sc128,
                                                    signed char* __restrict__ q8) {
    const int tid = blockIdx.x * blockDim.x + threadIdx.x;  // one 8-col chunk per thread
    if (blockIdx.x == 0 && threadIdx.x < DIM) {
        cmax_next[threadIdx.x * CMPAD] = 0;
        float mx = __builtin_bit_cast(float, cmax_cur[threadIdx.x * CMPAD]);
        sc128[threadIdx.x] = mx * (1.0f / 127.0f);
    }
    const int cb = (tid & 15) * 8;
    float inv[8];
#pragma unroll
    for (int k = 0; k < 8; k++) {
        float mx = __builtin_bit_cast(float, cmax_cur[(cb + k) * CMPAD]);
        inv[k] = mx > 0.f ? 127.0f / mx : 0.f;
    }
    u32x4 v = *(const u32x4*)(hb + (size_t)tid * 8);
    float f[8] = {bflo(v.x), bfhi(v.x), bflo(v.y), bfhi(v.y),
                  bflo(v.z), bfhi(v.z), bflo(v.w), bfhi(v.w)};
    unsigned int b[8];
#pragma unroll
    for (int k = 0; k < 8; k++) {
        int q = (int)rintf(f[k] * inv[k]);
        q = q > 127 ? 127 : (q < -127 ? -127 : q);  // guard bf16-vs-f32 max skew
        b[k] = (unsigned int)q & 255u;
    }
    u32x2 o;
    o.x = b[0] | (b[1] << 8) | (b[2] << 16) | (b[3] << 24);
    o.y = b[4] | (b[5] << 8) | (b[6] << 16) | (b[7] << 24);
    __builtin_nontemporal_store(o, (u32x2*)(q8 + (size_t)tid * 8));
}

// int8 gather pooling, R1 instruction shape: one wave per node, lane i owns
// cols 2i,2i+1. Each gather = ushort/lane x 64 lanes = 128B = ONE cache line
// (vs bf16's two), fully coalesced, one row per instruction, 8 edges in
// flight. int32 accumulate; dequant once per node from compact sc128.
__global__ __launch_bounds__(256) void pool_kernel(const signed char* __restrict__ q8,
                                                   const unsigned short* __restrict__ hb,
                                                   const int* __restrict__ row_start,
                                                   const int* __restrict__ col,
                                                   const float* __restrict__ eps_l,
                                                   const float* __restrict__ sc128,
                                                   unsigned short* __restrict__ pooled_b) {
    const int wave = threadIdx.x >> 6, lane = threadIdx.x & 63;
    const int n = blockIdx.x * 4 + wave;  // grid is exactly N_NODES/4 blocks
    const float ev = 1.0f + eps_l[0];
    const int s0 = row_start[n], s1 = row_start[n + 1];
    const int c2 = lane * 2;

    int i0 = 0, i1 = 0;
    for (int base = s0; base < s1; base += 64) {
        const int nn = (s1 - base < 64) ? (s1 - base) : 64;
        int ci = (base + lane < s1) ? __builtin_nontemporal_load(&col[base + lane]) : 0;
        for (int j = 0; j < nn; j += 8) {
            int s[8];
            unsigned short w[8];
#pragma unroll
            for (int q = 0; q < 8; q++) s[q] = __shfl(ci, j + q, 64);
#pragma unroll
            for (int q = 0; q < 8; q++)
                w[q] = *(const unsigned short*)(q8 + (size_t)s[q] * DIM + c2);
#pragma unroll
            for (int q = 0; q < 8; q++) {
                if (j + q < nn) {
                    i0 += (int)((signed char)(w[q] & 0xffu));
                    i1 += (int)((signed char)(w[q] >> 8));
                }
            }
        }
    }

    // self (exact bf16) + dequant, coalesced scale read
    unsigned int sv = *(const unsigned int*)(hb + (size_t)n * DIM + c2);
    float a0 = (float)i0 * sc128[c2] + ev * bflo(sv);
    float a1 = (float)i1 * sc128[c2 + 1] + ev * bfhi(sv);
    unsigned short u[2] = {f2bf(a0), f2bf(a1)};
    *(unsigned int*)(pooled_b + (size_t)n * DIM + c2) = *(unsigned int*)u;
}

// fused Linear1 -> ReLU -> Linear2 -> BN -> ReLU for a 64-row tile.
// Also produces per-column max of the output (for next layer's quantization).
__global__ __launch_bounds__(256) void mlp_kernel(
    const unsigned short* __restrict__ pooled_b,
    const unsigned short* __restrict__ wp1,
    const unsigned short* __restrict__ wp2,
    const float* __restrict__ b1,
    const float* __restrict__ b2,
    const float* __restrict__ bnscale,
    const float* __restrict__ bnshift,
    float* __restrict__ h_out,
    unsigned short* __restrict__ hb_out,
    unsigned int* __restrict__ cmax_next) {
    __shared__ __align__(16) unsigned short zfrag[4][4][64][8];  // z1 shuffle, wave-private
    __shared__ unsigned int cmg[DIM];
    const int tid = threadIdx.x;
    const int wave = tid >> 6, lane = tid & 63;
    const int m0 = blockIdx.x * 64;
    const int colc = lane & 15;
    const int quad = lane >> 4;
    const int arow = m0 + wave * 16 + colc;
    const int arow_c = arow < N_NODES ? arow : N_NODES - 1;
    if (tid < DIM) cmg[tid] = 0;

    bf16x8 a[4];
#pragma unroll
    for (int ks = 0; ks < 4; ks++)
        a[ks] = *(const bf16x8*)(pooled_b + arow_c * DIM + ks * 32 + quad * 8);

    f32x4 acc[8];
#pragma unroll
    for (int nt = 0; nt < 8; nt++) {
        acc[nt] = (f32x4){0.f, 0.f, 0.f, 0.f};
#pragma unroll
        for (int ks = 0; ks < 4; ks++) {
            bf16x8 b = *(const bf16x8*)(wp1 + ((ks * 8 + nt) * 64 + lane) * 8);
            acc[nt] = __builtin_amdgcn_mfma_f32_16x16x32_bf16(a[ks], b, acc[nt], 0, 0, 0);
        }
    }

    // bias + ReLU, write z1 to LDS in A-fragment layout (wave-private region)
#pragma unroll
    for (int nt = 0; nt < 8; nt++) {
        int n = nt * 16 + colc;
        float bias = b1[n];
#pragma unroll
        for (int r = 0; r < 4; r++) {
            float v = acc[nt][r] + bias;
            v = v > 0.f ? v : 0.f;
            int row16 = quad * 4 + r;
            zfrag[wave][n >> 5][(((n >> 3) & 3) << 4) | row16][n & 7] = f2bf(v);
        }
    }

#pragma unroll
    for (int ks = 0; ks < 4; ks++) a[ks] = *(const bf16x8*)(&zfrag[wave][ks][lane][0]);

    f32x4 acc2[8];
#pragma unroll
    for (int nt = 0; nt < 8; nt++) {
        acc2[nt] = (f32x4){0.f, 0.f, 0.f, 0.f};
#pragma unroll
        for (int ks = 0; ks < 4; ks++) {
            bf16x8 b = *(const bf16x8*)(wp2 + ((ks * 8 + nt) * 64 + lane) * 8);
            acc2[nt] = __builtin_amdgcn_mfma_f32_16x16x32_bf16(a[ks], b, acc2[nt], 0, 0, 0);
        }
    }

    // epilogue: +b2, BN, ReLU; fp32 out + bf16 shadow; track per-column max
    float cmx[8];
#pragma unroll
    for (int nt = 0; nt < 8; nt++) {
        int n = nt * 16 + colc;
        float bias = b2[n];
        float sc = bnscale[n], sh = bnshift[n];
        cmx[nt] = 0.f;
#pragma unroll
        for (int r = 0; r < 4; r++) {
            int row = m0 + wave * 16 + quad * 4 + r;
            if (row < N_NODES) {
                float z = acc2[nt][r] + bias;
                z = z * sc + sh;
                z = z > 0.f ? z : 0.f;
                __builtin_nontemporal_store(z, &h_out[row * DIM + n]);
                hb_out[row * DIM + n] = f2bf(z);
                cmx[nt] = fmaxf(cmx[nt], z);
            }
        }
    }
    __syncthreads();  // cmg zero-init visible
#pragma unroll
    for (int nt = 0; nt < 8; nt++)
        atomicMax(&cmg[nt * 16 + colc], __builtin_bit_cast(unsigned int, cmx[nt]));
    __syncthreads();
    if (tid < DIM) atomicMax(&cmax_next[tid * CMPAD], cmg[tid]);
}

// ---- launch --------------------------------------------------------------

extern "C" void kernel_launch(void* const* d_in, const int* in_sizes, int n_in,
                              void* d_out, int out_size, void* d_ws, size_t ws_size,
                              hipStream_t stream) {
    const float* x     = (const float*)d_in[0];
    const int* esrc    = (const int*)d_in[1];
    const int* edst    = (const int*)d_in[2];
    const float* eps   = (const float*)d_in[3];
    const float* W1    = (const float*)d_in[4];
    const float* b1    = (const float*)d_in[5];
    const float* W2    = (const float*)d_in[6];
    const float* b2    = (const float*)d_in[7];
    const float* gam   = (const float*)d_in[8];
    const float* bet   = (const float*)d_in[9];
    const float* bmean = (const float*)d_in[10];
    const float* bvar  = (const float*)d_in[11];
    float* out = (float*)d_out;

    char* ws = (char*)d_ws;
    unsigned short* hb  = (unsigned short*)(ws);                // 12,800,000 B
    int*   col        = (int*)  (ws + 12800000);                //  3,200,000 B
    int*   row_start  = (int*)  (ws + 16000000);                //    200,004 B
    int*   cursor     = (int*)  (ws + 16200192);                //    200,000 B
    int*   cnt        = (int*)  (ws + 16400384);                //    200,000 B
    unsigned short* wpack = (unsigned short*)(ws + 16600576);   //    327,680 B
    float* bnscale    = (float*)(ws + 16928256);                //      2,560 B
    float* bnshift    = (float*)(ws + 16930816);                //      2,560 B
    unsigned int* cmax = (unsigned int*)(ws + 16933376);        //     16,384 B (2 slots)
    float* sc128      = (float*)(ws + 16949760);                //        512 B
    signed char* q8   = (signed char*)(ws + 16950272);          //  6,400,000 B
    unsigned short* pooled_b = (unsigned short*)(ws + 23350272); // 12,800,000 B

    init_zero_kernel<<<(1600000 + N_NODES + 2 * DIM * CMPAD + 255) / 256, 256, 0, stream>>>(
        x, out, hb, cnt, cmax);
    colmax0_kernel<<<256, 256, 0, stream>>>(hb, cmax);
    hist_kernel<<<(N_EDGES + 255) / 256, 256, 0, stream>>>(edst, cnt);
    scan_kernel<<<1, 1024, 0, stream>>>(cnt, row_start, cursor);
    fill_kernel<<<(N_EDGES + 255) / 256, 256, 0, stream>>>(esrc, edst, cursor, col);
    prep_kernel<<<(N_LAYERS * 2 * 2048 + N_LAYERS * DIM + 255) / 256, 256, 0, stream>>>(
        W1, W2, wpack, gam, bet, bmean, bvar, bnscale, bnshift);

    const int quant_blocks = (N_NODES * DIM / 8) / 256;  // 3125
    const int pool_blocks  = N_NODES / 4;                // 12500
    const int mlp_blocks   = (N_NODES + 63) / 64;        // 782
    for (int l = 0; l < N_LAYERS; l++) {
        float* h_next = out + (size_t)(l + 1) * N_NODES * DIM;
        unsigned int* cm_cur  = cmax + (size_t)(l & 1) * DIM * CMPAD;
        unsigned int* cm_next = cmax + (size_t)((l + 1) & 1) * DIM * CMPAD;
        quant_kernel<<<quant_blocks, 256, 0, stream>>>(hb, cm_cur, cm_next, sc128, q8);
        pool_kernel<<<pool_blocks, 256, 0, stream>>>(q8, hb, row_start, col, eps + l,
                                                     sc128, pooled_b);
        mlp_kernel<<<mlp_blocks, 256, 0, stream>>>(
            pooled_b,
            wpack + (size_t)(l * 2) * 16384,
            wpack + (size_t)(l * 2 + 1) * 16384,
            b1 + l * DIM, b2 + l * DIM,
            bnscale + l * DIM, bnshift + l * DIM,
            h_next, hb, cm_next);
    }
}

// Round 7
// 692.676 us; speedup vs baseline: 1.1850x; 1.0296x over previous
//
#include <hip/hip_runtime.h>
#include <hip/hip_bf16.h>

#define N_NODES 50000
#define N_EDGES 800000
#define DIM 128
#define N_LAYERS 5
#define BN_EPS 1e-3f
#define CMPAD 16  // floats per column slot (64B padding to spread atomics)

typedef __attribute__((ext_vector_type(8))) short bf16x8;
typedef __attribute__((ext_vector_type(4))) float f32x4;
typedef __attribute__((ext_vector_type(4))) unsigned int u32x4;
typedef __attribute__((ext_vector_type(2))) unsigned int u32x2;

__device__ __forceinline__ unsigned short f2bf(float f) {
    unsigned int v = __builtin_bit_cast(unsigned int, f);
    v += 0x7fffu + ((v >> 16) & 1u);
    return (unsigned short)(v >> 16);
}
__device__ __forceinline__ float bflo(unsigned int v) {
    return __builtin_bit_cast(float, v << 16);
}
__device__ __forceinline__ float bfhi(unsigned int v) {
    return __builtin_bit_cast(float, v & 0xffff0000u);
}

// ---- setup kernels -------------------------------------------------------

// copy x -> out chunk 0 (fp32) + hb (bf16 shadow, row-major); zero cnt + cmax
__global__ void init_zero_kernel(const float* __restrict__ x, float* __restrict__ out,
                                 unsigned short* __restrict__ hb, int* __restrict__ cnt,
                                 unsigned int* __restrict__ cmax) {
    int t = blockIdx.x * blockDim.x + threadIdx.x;
    if (t < (N_NODES * DIM) / 4) {
        f32x4 v = ((const f32x4*)x)[t];
        __builtin_nontemporal_store(v, (f32x4*)out + t);
        unsigned short u[4] = {f2bf(v.x), f2bf(v.y), f2bf(v.z), f2bf(v.w)};
        *(u32x2*)(hb + t * 4) = *(u32x2*)u;
    }
    int z = t - (N_NODES * DIM) / 4;
    if (z >= 0 && z < N_NODES) cnt[z] = 0;
    int z2 = z - N_NODES;
    if (z2 >= 0 && z2 < 2 * DIM * CMPAD) cmax[z2] = 0;
}

// per-column absmax of hb (bf16) -> cmax slot 0 (float bits, values >= 0)
__global__ __launch_bounds__(256) void colmax0_kernel(const unsigned short* __restrict__ hb,
                                                      unsigned int* __restrict__ cmax) {
    __shared__ unsigned int cm[DIM];
    const int tid = threadIdx.x;
    if (tid < DIM) cm[tid] = 0;
    __syncthreads();
    const int total = N_NODES * DIM / 8;     // 16B chunks
    const int stride = gridDim.x * blockDim.x;  // 65536, %16==0 -> col phase invariant
    float m[8] = {0.f, 0.f, 0.f, 0.f, 0.f, 0.f, 0.f, 0.f};
    for (int e = blockIdx.x * blockDim.x + tid; e < total; e += stride) {
        u32x4 v = *(const u32x4*)(hb + (size_t)e * 8);
        m[0] = fmaxf(m[0], fabsf(bflo(v.x))); m[1] = fmaxf(m[1], fabsf(bfhi(v.x)));
        m[2] = fmaxf(m[2], fabsf(bflo(v.y))); m[3] = fmaxf(m[3], fabsf(bfhi(v.y)));
        m[4] = fmaxf(m[4], fabsf(bflo(v.z))); m[5] = fmaxf(m[5], fabsf(bfhi(v.z)));
        m[6] = fmaxf(m[6], fabsf(bflo(v.w))); m[7] = fmaxf(m[7], fabsf(bfhi(v.w)));
    }
    const int cb = (tid & 15) * 8;
#pragma unroll
    for (int k = 0; k < 8; k++)
        atomicMax(&cm[cb + k], __builtin_bit_cast(unsigned int, m[k]));
    __syncthreads();
    if (tid < DIM) atomicMax(&cmax[tid * CMPAD], cm[tid]);
}

__global__ void hist_kernel(const int* __restrict__ dst, int* __restrict__ cnt) {
    int e = blockIdx.x * blockDim.x + threadIdx.x;
    if (e < N_EDGES) atomicAdd(&cnt[dst[e]], 1);
}

// single-block exclusive scan of cnt[0..N_NODES) -> row_start, cursor
__global__ __launch_bounds__(1024) void scan_kernel(const int* __restrict__ cnt,
                                                    int* __restrict__ row_start,
                                                    int* __restrict__ cursor) {
    __shared__ int wsum[16];
    __shared__ int s_carry;
    const int tid = threadIdx.x;
    const int lane = tid & 63, wave = tid >> 6;
    if (tid == 0) s_carry = 0;
    __syncthreads();
    for (int base = 0; base < N_NODES; base += 4096) {
        int i0 = base + tid * 4;
        int v[4];
#pragma unroll
        for (int j = 0; j < 4; j++) {
            int i = i0 + j;
            v[j] = (i < N_NODES) ? cnt[i] : 0;
        }
        int s = v[0] + v[1] + v[2] + v[3];
        int x = s;
#pragma unroll
        for (int off = 1; off < 64; off <<= 1) {
            int t = __shfl_up(x, off, 64);
            if (lane >= off) x += t;
        }
        if (lane == 63) wsum[wave] = x;
        __syncthreads();
        if (wave == 0) {
            int w = (lane < 16) ? wsum[lane] : 0;
#pragma unroll
            for (int off = 1; off < 16; off <<= 1) {
                int t = __shfl_up(w, off, 64);
                if (lane >= off) w += t;
            }
            if (lane < 16) wsum[lane] = w;
        }
        __syncthreads();
        int waveoff = (wave > 0) ? wsum[wave - 1] : 0;
        int carry = s_carry;
        int run = carry + waveoff + (x - s);
#pragma unroll
        for (int j = 0; j < 4; j++) {
            int i = i0 + j;
            if (i < N_NODES) { row_start[i] = run; cursor[i] = run; }
            run += v[j];
        }
        __syncthreads();
        if (tid == 1023) s_carry = carry + wsum[15];
        __syncthreads();
    }
    if (tid == 0) row_start[N_NODES] = s_carry;
}

__global__ void fill_kernel(const int* __restrict__ src, const int* __restrict__ dst,
                            int* __restrict__ cursor, int* __restrict__ col) {
    int e = blockIdx.x * blockDim.x + threadIdx.x;
    if (e < N_EDGES) {
        int d = dst[e];
        int pos = atomicAdd(&cursor[d], 1);
        col[pos] = src[e];
    }
}

// pack W1/W2 (fp32->bf16) into B-fragment order + fold BN scale/shift
__global__ void prep_kernel(const float* __restrict__ W1, const float* __restrict__ W2,
                            unsigned short* __restrict__ wp,
                            const float* __restrict__ gamma, const float* __restrict__ beta,
                            const float* __restrict__ mean, const float* __restrict__ var,
                            float* __restrict__ scale, float* __restrict__ shift) {
    int t = blockIdx.x * blockDim.x + threadIdx.x;
    if (t < N_LAYERS * 2 * 2048) {
        int mat = t >> 11;
        int r = t & 2047;
        int ks = r >> 9, nt = (r >> 6) & 7, lane = r & 63;
        int layer = mat >> 1;
        const float* W = ((mat & 1) ? W2 : W1) + layer * DIM * DIM;
        int n = nt * 16 + (lane & 15);
        int kb = ks * 32 + (lane >> 4) * 8;
        unsigned short u[8];
#pragma unroll
        for (int j = 0; j < 8; j++) u[j] = f2bf(W[(kb + j) * DIM + n]);
        *(u32x4*)(wp + (size_t)mat * 16384 + ((ks * 8 + nt) * 64 + lane) * 8) = *(u32x4*)u;
    }
    int i = t - N_LAYERS * 2 * 2048;
    if (i >= 0 && i < N_LAYERS * DIM) {
        float sc = gamma[i] * rsqrtf(var[i] + BN_EPS);
        scale[i] = sc;
        shift[i] = beta[i] - mean[i] * sc;
    }
}

// ---- per-layer kernels ---------------------------------------------------

// quantize hb (bf16, row-major) -> q8 int8 with per-column scale 127/cmax.
// Block 0 also zeroes the NEXT cmax slot and emits the compact dequant
// scale array sc128[c] = cmax[c]/127 (pool reads it coalesced).
__global__ __launch_bounds__(256) void quant_kernel(const unsigned short* __restrict__ hb,
                                                    const unsigned int* __restrict__ cmax_cur,
                                                    unsigned int* __restrict__ cmax_next,
                                                    float* __restrict__ sc128,
                                                    signed char* __restrict__ q8) {
    const int tid = blockIdx.x * blockDim.x + threadIdx.x;  // one 8-col chunk per thread
    if (blockIdx.x == 0 && threadIdx.x < DIM) {
        cmax_next[threadIdx.x * CMPAD] = 0;
        float mx = __builtin_bit_cast(float, cmax_cur[threadIdx.x * CMPAD]);
        sc128[threadIdx.x] = mx * (1.0f / 127.0f);
    }
    const int cb = (tid & 15) * 8;
    float inv[8];
#pragma unroll
    for (int k = 0; k < 8; k++) {
        float mx = __builtin_bit_cast(float, cmax_cur[(cb + k) * CMPAD]);
        inv[k] = mx > 0.f ? 127.0f / mx : 0.f;
    }
    u32x4 v = *(const u32x4*)(hb + (size_t)tid * 8);
    float f[8] = {bflo(v.x), bfhi(v.x), bflo(v.y), bfhi(v.y),
                  bflo(v.z), bfhi(v.z), bflo(v.w), bfhi(v.w)};
    unsigned int b[8];
#pragma unroll
    for (int k = 0; k < 8; k++) {
        int q = (int)rintf(f[k] * inv[k]);
        q = q > 127 ? 127 : (q < -127 ? -127 : q);  // guard bf16-vs-f32 max skew
        b[k] = (unsigned int)q & 255u;
    }
    u32x2 o;
    o.x = b[0] | (b[1] << 8) | (b[2] << 16) | (b[3] << 24);
    o.y = b[4] | (b[5] << 8) | (b[6] << 16) | (b[7] << 24);
    __builtin_nontemporal_store(o, (u32x2*)(q8 + (size_t)tid * 8));
}

// int8 gather pooling, DWORD lanes (no sub-dword loads), 2 rows/instruction:
// half h = lane>>5 covers edge 2k+h's full 128B row; lane32 = lane&31 covers
// cols 4*lane32..4*lane32+3. One cache line per edge, 8 loads in flight
// (16 edges -- the average degree -- per batch). int32 per-column accumulate,
// shfl_xor(32) combine, single dequant from compact coalesced sc128.
__global__ __launch_bounds__(256) void pool_kernel(const signed char* __restrict__ q8,
                                                   const unsigned short* __restrict__ hb,
                                                   const int* __restrict__ row_start,
                                                   const int* __restrict__ col,
                                                   const float* __restrict__ eps_l,
                                                   const float* __restrict__ sc128,
                                                   unsigned short* __restrict__ pooled_b) {
    const int wave = threadIdx.x >> 6, lane = threadIdx.x & 63;
    const int n = blockIdx.x * 4 + wave;  // grid is exactly N_NODES/4 blocks
    const float ev = 1.0f + eps_l[0];
    const int s0 = row_start[n], s1 = row_start[n + 1];
    const int h = lane >> 5;        // which edge of the pair this lane serves
    const int lane32 = lane & 31;   // dword index within the 128B row

    int a0 = 0, a1 = 0, a2 = 0, a3 = 0;
    for (int base = s0; base < s1; base += 64) {
        const int nn = (s1 - base < 64) ? (s1 - base) : 64;
        int ci = (base + lane < s1) ? __builtin_nontemporal_load(&col[base + lane]) : 0;
        for (int j = 0; j < nn; j += 16) {
            int s[8];
            unsigned int w[8];
#pragma unroll
            for (int q = 0; q < 8; q++) s[q] = __shfl(ci, j + 2 * q + h, 64);
#pragma unroll
            for (int q = 0; q < 8; q++) {
                if (j + 2 * q < nn)  // wave-uniform: skip pairs fully past nn
                    w[q] = *(const unsigned int*)(q8 + (size_t)s[q] * DIM + lane32 * 4);
            }
#pragma unroll
            for (int q = 0; q < 8; q++) {
                if (j + 2 * q < nn) {
                    // per-lane mask: this half's edge may be the odd tail
                    if (j + 2 * q + h < nn) {
                        unsigned int v = w[q];
                        a0 += (int)((signed char)(v & 0xffu));
                        a1 += (int)((signed char)((v >> 8) & 0xffu));
                        a2 += (int)((signed char)((v >> 16) & 0xffu));
                        a3 += (int)((signed char)(v >> 24));
                    }
                }
            }
        }
    }

    // combine the two half partials
    a0 += __shfl_xor(a0, 32, 64);
    a1 += __shfl_xor(a1, 32, 64);
    a2 += __shfl_xor(a2, 32, 64);
    a3 += __shfl_xor(a3, 32, 64);

    if (h == 0) {
        // self (exact bf16): cols 4*lane32 .. 4*lane32+3
        u32x2 sv = *(const u32x2*)(hb + (size_t)n * DIM + lane32 * 4);
        f32x4 sc = ((const f32x4*)sc128)[lane32];
        float f0 = (float)a0 * sc.x + ev * bflo(sv.x);
        float f1 = (float)a1 * sc.y + ev * bfhi(sv.x);
        float f2 = (float)a2 * sc.z + ev * bflo(sv.y);
        float f3 = (float)a3 * sc.w + ev * bfhi(sv.y);
        unsigned short u[4] = {f2bf(f0), f2bf(f1), f2bf(f2), f2bf(f3)};
        *(u32x2*)(pooled_b + (size_t)n * DIM + lane32 * 4) = *(u32x2*)u;
    }
}

// fused Linear1 -> ReLU -> Linear2 -> BN -> ReLU for a 64-row tile.
// Also produces per-column max of the output (for next layer's quantization).
__global__ __launch_bounds__(256) void mlp_kernel(
    const unsigned short* __restrict__ pooled_b,
    const unsigned short* __restrict__ wp1,
    const unsigned short* __restrict__ wp2,
    const float* __restrict__ b1,
    const float* __restrict__ b2,
    const float* __restrict__ bnscale,
    const float* __restrict__ bnshift,
    float* __restrict__ h_out,
    unsigned short* __restrict__ hb_out,
    unsigned int* __restrict__ cmax_next) {
    __shared__ __align__(16) unsigned short zfrag[4][4][64][8];  // z1 shuffle, wave-private
    __shared__ unsigned int cmg[DIM];
    const int tid = threadIdx.x;
    const int wave = tid >> 6, lane = tid & 63;
    const int m0 = blockIdx.x * 64;
    const int colc = lane & 15;
    const int quad = lane >> 4;
    const int arow = m0 + wave * 16 + colc;
    const int arow_c = arow < N_NODES ? arow : N_NODES - 1;
    if (tid < DIM) cmg[tid] = 0;

    bf16x8 a[4];
#pragma unroll
    for (int ks = 0; ks < 4; ks++)
        a[ks] = *(const bf16x8*)(pooled_b + arow_c * DIM + ks * 32 + quad * 8);

    f32x4 acc[8];
#pragma unroll
    for (int nt = 0; nt < 8; nt++) {
        acc[nt] = (f32x4){0.f, 0.f, 0.f, 0.f};
#pragma unroll
        for (int ks = 0; ks < 4; ks++) {
            bf16x8 b = *(const bf16x8*)(wp1 + ((ks * 8 + nt) * 64 + lane) * 8);
            acc[nt] = __builtin_amdgcn_mfma_f32_16x16x32_bf16(a[ks], b, acc[nt], 0, 0, 0);
        }
    }

    // bias + ReLU, write z1 to LDS in A-fragment layout (wave-private region)
#pragma unroll
    for (int nt = 0; nt < 8; nt++) {
        int n = nt * 16 + colc;
        float bias = b1[n];
#pragma unroll
        for (int r = 0; r < 4; r++) {
            float v = acc[nt][r] + bias;
            v = v > 0.f ? v : 0.f;
            int row16 = quad * 4 + r;
            zfrag[wave][n >> 5][(((n >> 3) & 3) << 4) | row16][n & 7] = f2bf(v);
        }
    }

#pragma unroll
    for (int ks = 0; ks < 4; ks++) a[ks] = *(const bf16x8*)(&zfrag[wave][ks][lane][0]);

    f32x4 acc2[8];
#pragma unroll
    for (int nt = 0; nt < 8; nt++) {
        acc2[nt] = (f32x4){0.f, 0.f, 0.f, 0.f};
#pragma unroll
        for (int ks = 0; ks < 4; ks++) {
            bf16x8 b = *(const bf16x8*)(wp2 + ((ks * 8 + nt) * 64 + lane) * 8);
            acc2[nt] = __builtin_amdgcn_mfma_f32_16x16x32_bf16(a[ks], b, acc2[nt], 0, 0, 0);
        }
    }

    // epilogue: +b2, BN, ReLU; fp32 out + bf16 shadow; track per-column max
    float cmx[8];
#pragma unroll
    for (int nt = 0; nt < 8; nt++) {
        int n = nt * 16 + colc;
        float bias = b2[n];
        float sc = bnscale[n], sh = bnshift[n];
        cmx[nt] = 0.f;
#pragma unroll
        for (int r = 0; r < 4; r++) {
            int row = m0 + wave * 16 + quad * 4 + r;
            if (row < N_NODES) {
                float z = acc2[nt][r] + bias;
                z = z * sc + sh;
                z = z > 0.f ? z : 0.f;
                __builtin_nontemporal_store(z, &h_out[row * DIM + n]);
                hb_out[row * DIM + n] = f2bf(z);
                cmx[nt] = fmaxf(cmx[nt], z);
            }
        }
    }
    __syncthreads();  // cmg zero-init visible
#pragma unroll
    for (int nt = 0; nt < 8; nt++)
        atomicMax(&cmg[nt * 16 + colc], __builtin_bit_cast(unsigned int, cmx[nt]));
    __syncthreads();
    if (tid < DIM) atomicMax(&cmax_next[tid * CMPAD], cmg[tid]);
}

// ---- launch --------------------------------------------------------------

extern "C" void kernel_launch(void* const* d_in, const int* in_sizes, int n_in,
                              void* d_out, int out_size, void* d_ws, size_t ws_size,
                              hipStream_t stream) {
    const float* x     = (const float*)d_in[0];
    const int* esrc    = (const int*)d_in[1];
    const int* edst    = (const int*)d_in[2];
    const float* eps   = (const float*)d_in[3];
    const float* W1    = (const float*)d_in[4];
    const float* b1    = (const float*)d_in[5];
    const float* W2    = (const float*)d_in[6];
    const float* b2    = (const float*)d_in[7];
    const float* gam   = (const float*)d_in[8];
    const float* bet   = (const float*)d_in[9];
    const float* bmean = (const float*)d_in[10];
    const float* bvar  = (const float*)d_in[11];
    float* out = (float*)d_out;

    char* ws = (char*)d_ws;
    unsigned short* hb  = (unsigned short*)(ws);                // 12,800,000 B
    int*   col        = (int*)  (ws + 12800000);                //  3,200,000 B
    int*   row_start  = (int*)  (ws + 16000000);                //    200,004 B
    int*   cursor     = (int*)  (ws + 16200192);                //    200,000 B
    int*   cnt        = (int*)  (ws + 16400384);                //    200,000 B
    unsigned short* wpack = (unsigned short*)(ws + 16600576);   //    327,680 B
    float* bnscale    = (float*)(ws + 16928256);                //      2,560 B
    float* bnshift    = (float*)(ws + 16930816);                //      2,560 B
    unsigned int* cmax = (unsigned int*)(ws + 16933376);        //     16,384 B (2 slots)
    float* sc128      = (float*)(ws + 16949760);                //        512 B
    signed char* q8   = (signed char*)(ws + 16950272);          //  6,400,000 B
    unsigned short* pooled_b = (unsigned short*)(ws + 23350272); // 12,800,000 B

    init_zero_kernel<<<(1600000 + N_NODES + 2 * DIM * CMPAD + 255) / 256, 256, 0, stream>>>(
        x, out, hb, cnt, cmax);
    colmax0_kernel<<<256, 256, 0, stream>>>(hb, cmax);
    hist_kernel<<<(N_EDGES + 255) / 256, 256, 0, stream>>>(edst, cnt);
    scan_kernel<<<1, 1024, 0, stream>>>(cnt, row_start, cursor);
    fill_kernel<<<(N_EDGES + 255) / 256, 256, 0, stream>>>(esrc, edst, cursor, col);
    prep_kernel<<<(N_LAYERS * 2 * 2048 + N_LAYERS * DIM + 255) / 256, 256, 0, stream>>>(
        W1, W2, wpack, gam, bet, bmean, bvar, bnscale, bnshift);

    const int quant_blocks = (N_NODES * DIM / 8) / 256;  // 3125
    const int pool_blocks  = N_NODES / 4;                // 12500
    const int mlp_blocks   = (N_NODES + 63) / 64;        // 782
    for (int l = 0; l < N_LAYERS; l++) {
        float* h_next = out + (size_t)(l + 1) * N_NODES * DIM;
        unsigned int* cm_cur  = cmax + (size_t)(l & 1) * DIM * CMPAD;
        unsigned int* cm_next = cmax + (size_t)((l + 1) & 1) * DIM * CMPAD;
        quant_kernel<<<quant_blocks, 256, 0, stream>>>(hb, cm_cur, cm_next, sc128, q8);
        pool_kernel<<<pool_blocks, 256, 0, stream>>>(q8, hb, row_start, col, eps + l,
                                                     sc128, pooled_b);
        mlp_kernel<<<mlp_blocks, 256, 0, stream>>>(
            pooled_b,
            wpack + (size_t)(l * 2) * 16384,
            wpack + (size_t)(l * 2 + 1) * 16384,
            b1 + l * DIM, b2 + l * DIM,
            bnscale + l * DIM, bnshift + l * DIM,
            h_next, hb, cm_next);
    }
}

// Round 8
// 537.751 us; speedup vs baseline: 1.5264x; 1.2881x over previous
//
#include <hip/hip_runtime.h>
#include <hip/hip_bf16.h>

#define N_NODES 50000
#define N_EDGES 800000
#define DIM 128
#define N_LAYERS 5
#define BN_EPS 1e-3f
#define NBLK_SCAN ((N_NODES + 255) / 256)  // 196

typedef __attribute__((ext_vector_type(8))) short bf16x8;
typedef __attribute__((ext_vector_type(4))) float f32x4;
typedef __attribute__((ext_vector_type(4))) unsigned int u32x4;
typedef __attribute__((ext_vector_type(2))) unsigned int u32x2;

__device__ __forceinline__ unsigned short f2bf(float f) {
    unsigned int v = __builtin_bit_cast(unsigned int, f);
    v += 0x7fffu + ((v >> 16) & 1u);
    return (unsigned short)(v >> 16);
}
__device__ __forceinline__ float bflo(unsigned int v) {
    return __builtin_bit_cast(float, v << 16);
}
__device__ __forceinline__ float bfhi(unsigned int v) {
    return __builtin_bit_cast(float, v & 0xffff0000u);
}

// ---- setup kernels -------------------------------------------------------

// copy x -> out chunk 0 (fp32) + hb0 (bf16 shadow); also zero cnt[]
__global__ void init_zero_kernel(const float* __restrict__ x, float* __restrict__ out,
                                 unsigned short* __restrict__ hb, int* __restrict__ cnt) {
    int t = blockIdx.x * blockDim.x + threadIdx.x;
    if (t < (N_NODES * DIM) / 4) {
        f32x4 v = ((const f32x4*)x)[t];
        __builtin_nontemporal_store(v, (f32x4*)out + t);
        unsigned short u[4] = {f2bf(v.x), f2bf(v.y), f2bf(v.z), f2bf(v.w)};
        *(u32x2*)(hb + t * 4) = *(u32x2*)u;
    }
    int z = t - (N_NODES * DIM) / 4;
    if (z >= 0 && z < N_NODES) cnt[z] = 0;
}

__global__ void hist_kernel(const int* __restrict__ dst, int* __restrict__ cnt) {
    int e = blockIdx.x * blockDim.x + threadIdx.x;
    if (e < N_EDGES) atomicAdd(&cnt[dst[e]], 1);
}

// parallel scan, 3 dispatches (replaces the 1-block serial scan):
// A: per-256-chunk sums  B: 1-block exclusive scan of 196 partials  C: rescan+offset
__global__ __launch_bounds__(256) void scanA_kernel(const int* __restrict__ cnt,
                                                    int* __restrict__ blocksum) {
    const int tid = threadIdx.x, lane = tid & 63, wave = tid >> 6;
    int i = blockIdx.x * 256 + tid;
    int v = (i < N_NODES) ? cnt[i] : 0;
#pragma unroll
    for (int off = 1; off < 64; off <<= 1) v += __shfl_xor(v, off, 64);
    __shared__ int ws[4];
    if (lane == 0) ws[wave] = v;
    __syncthreads();
    if (tid == 0) blocksum[blockIdx.x] = ws[0] + ws[1] + ws[2] + ws[3];
}

__global__ __launch_bounds__(256) void scanB_kernel(int* __restrict__ blocksum,
                                                    int* __restrict__ row_start) {
    __shared__ int s[256];
    const int tid = threadIdx.x;
    int v = (tid < NBLK_SCAN) ? blocksum[tid] : 0;
    s[tid] = v;
    __syncthreads();
#pragma unroll
    for (int off = 1; off < 256; off <<= 1) {
        int t = (tid >= off) ? s[tid - off] : 0;
        __syncthreads();
        s[tid] += t;
        __syncthreads();
    }
    if (tid < NBLK_SCAN) blocksum[tid] = s[tid] - v;  // exclusive block offset
    if (tid == 0) row_start[N_NODES] = N_EDGES;
}

__global__ __launch_bounds__(256) void scanC_kernel(const int* __restrict__ cnt,
                                                    const int* __restrict__ blockoff,
                                                    int* __restrict__ row_start,
                                                    int* __restrict__ cursor) {
    const int tid = threadIdx.x, lane = tid & 63, wave = tid >> 6;
    int i = blockIdx.x * 256 + tid;
    int v = (i < N_NODES) ? cnt[i] : 0;
    int x = v;
#pragma unroll
    for (int off = 1; off < 64; off <<= 1) {
        int t = __shfl_up(x, off, 64);
        if (lane >= off) x += t;
    }
    __shared__ int ws[4];
    if (lane == 63) ws[wave] = x;
    __syncthreads();
    int woff = 0;
    if (wave > 0) woff += ws[0];
    if (wave > 1) woff += ws[1];
    if (wave > 2) woff += ws[2];
    int excl = blockoff[blockIdx.x] + woff + x - v;
    if (i < N_NODES) { row_start[i] = excl; cursor[i] = excl; }
}

__global__ void fill_kernel(const int* __restrict__ src, const int* __restrict__ dst,
                            int* __restrict__ cursor, int* __restrict__ col) {
    int e = blockIdx.x * blockDim.x + threadIdx.x;
    if (e < N_EDGES) {
        int d = dst[e];
        int pos = atomicAdd(&cursor[d], 1);
        col[pos] = src[e];
    }
}

// pack W1/W2 (fp32->bf16) into B-fragment order + fold BN scale/shift
__global__ void prep_kernel(const float* __restrict__ W1, const float* __restrict__ W2,
                            unsigned short* __restrict__ wp,
                            const float* __restrict__ gamma, const float* __restrict__ beta,
                            const float* __restrict__ mean, const float* __restrict__ var,
                            float* __restrict__ scale, float* __restrict__ shift) {
    int t = blockIdx.x * blockDim.x + threadIdx.x;
    if (t < N_LAYERS * 2 * 2048) {
        int mat = t >> 11;
        int r = t & 2047;
        int ks = r >> 9, nt = (r >> 6) & 7, lane = r & 63;
        int layer = mat >> 1;
        const float* W = ((mat & 1) ? W2 : W1) + layer * DIM * DIM;
        int n = nt * 16 + (lane & 15);
        int kb = ks * 32 + (lane >> 4) * 8;
        unsigned short u[8];
#pragma unroll
        for (int j = 0; j < 8; j++) u[j] = f2bf(W[(kb + j) * DIM + n]);
        *(u32x4*)(wp + (size_t)mat * 16384 + ((ks * 8 + nt) * 64 + lane) * 8) = *(u32x4*)u;
    }
    int i = t - N_LAYERS * 2 * 2048;
    if (i >= 0 && i < N_LAYERS * DIM) {
        float sc = gamma[i] * rsqrtf(var[i] + BN_EPS);
        scale[i] = sc;
        shift[i] = beta[i] - mean[i] * sc;
    }
}

// ---- per-layer kernels ---------------------------------------------------

// one wave per node; lane i holds cols 2i, 2i+1 (one dword of 2 bf16 per row).
// 8 independent row-gathers in flight; masked accumulate kills the serial tail.
// (measured-optimal gather shape: 64x4B fully-coalesced single-segment request;
//  five alternative formats incl. int8 all regressed -- fabric is request-bound)
__global__ __launch_bounds__(256) void pool_kernel(const unsigned short* __restrict__ hb,
                                                   const int* __restrict__ row_start,
                                                   const int* __restrict__ col,
                                                   const float* __restrict__ eps_l,
                                                   unsigned short* __restrict__ pooled_b) {
    const int wave = threadIdx.x >> 6, lane = threadIdx.x & 63;
    const int n = blockIdx.x * 4 + wave;
    if (n >= N_NODES) return;
    const float ev = 1.0f + eps_l[0];
    const int s0 = row_start[n], s1 = row_start[n + 1];
    const int c2 = lane * 2;

    unsigned int sv = *(const unsigned int*)(hb + n * DIM + c2);
    float a0 = ev * bflo(sv);
    float a1 = ev * bfhi(sv);

    for (int base = s0; base < s1; base += 64) {
        const int nn = (s1 - base < 64) ? (s1 - base) : 64;
        int ci = (base + lane < s1) ? col[base + lane] : 0;
        for (int j = 0; j < nn; j += 8) {
            int s[8];
            unsigned int v[8];
#pragma unroll
            for (int q = 0; q < 8; q++) s[q] = __shfl(ci, j + q, 64);
#pragma unroll
            for (int q = 0; q < 8; q++)
                v[q] = *(const unsigned int*)(hb + s[q] * DIM + c2);
#pragma unroll
            for (int q = 0; q < 8; q++) {
                if (j + q < nn) { a0 += bflo(v[q]); a1 += bfhi(v[q]); }
            }
        }
    }
    unsigned short u[2] = {f2bf(a0), f2bf(a1)};
    *(unsigned int*)(pooled_b + n * DIM + c2) = *(unsigned int*)u;
}

// fused Linear1 -> ReLU -> Linear2 -> BN -> ReLU for a 64-row tile.
// A-fragments loaded straight from bf16 row-major pooled_b (no LDS staging).
__global__ __launch_bounds__(256) void mlp_kernel(
    const unsigned short* __restrict__ pooled_b,
    const unsigned short* __restrict__ wp1,
    const unsigned short* __restrict__ wp2,
    const float* __restrict__ b1,
    const float* __restrict__ b2,
    const float* __restrict__ bnscale,
    const float* __restrict__ bnshift,
    float* __restrict__ h_out,
    unsigned short* __restrict__ hb_out) {
    __shared__ __align__(16) unsigned short zfrag[4][4][64][8];  // z1 shuffle, wave-private
    const int tid = threadIdx.x;
    const int wave = tid >> 6, lane = tid & 63;
    const int m0 = blockIdx.x * 64;
    const int colc = lane & 15;
    const int quad = lane >> 4;
    const int arow = m0 + wave * 16 + colc;
    const int arow_c = arow < N_NODES ? arow : N_NODES - 1;

    bf16x8 a[4];
#pragma unroll
    for (int ks = 0; ks < 4; ks++)
        a[ks] = *(const bf16x8*)(pooled_b + arow_c * DIM + ks * 32 + quad * 8);

    f32x4 acc[8];
#pragma unroll
    for (int nt = 0; nt < 8; nt++) {
        acc[nt] = (f32x4){0.f, 0.f, 0.f, 0.f};
#pragma unroll
        for (int ks = 0; ks < 4; ks++) {
            bf16x8 b = *(const bf16x8*)(wp1 + ((ks * 8 + nt) * 64 + lane) * 8);
            acc[nt] = __builtin_amdgcn_mfma_f32_16x16x32_bf16(a[ks], b, acc[nt], 0, 0, 0);
        }
    }

    // bias + ReLU, write z1 to LDS in A-fragment layout (wave-private region)
#pragma unroll
    for (int nt = 0; nt < 8; nt++) {
        int n = nt * 16 + colc;
        float bias = b1[n];
#pragma unroll
        for (int r = 0; r < 4; r++) {
            float v = acc[nt][r] + bias;
            v = v > 0.f ? v : 0.f;
            int row16 = quad * 4 + r;
            zfrag[wave][n >> 5][(((n >> 3) & 3) << 4) | row16][n & 7] = f2bf(v);
        }
    }

#pragma unroll
    for (int ks = 0; ks < 4; ks++) a[ks] = *(const bf16x8*)(&zfrag[wave][ks][lane][0]);

    f32x4 acc2[8];
#pragma unroll
    for (int nt = 0; nt < 8; nt++) {
        acc2[nt] = (f32x4){0.f, 0.f, 0.f, 0.f};
#pragma unroll
        for (int ks = 0; ks < 4; ks++) {
            bf16x8 b = *(const bf16x8*)(wp2 + ((ks * 8 + nt) * 64 + lane) * 8);
            acc2[nt] = __builtin_amdgcn_mfma_f32_16x16x32_bf16(a[ks], b, acc2[nt], 0, 0, 0);
        }
    }

    // epilogue: +b2, BN, ReLU; nontemporal fp32 out (write-only) + bf16 shadow
#pragma unroll
    for (int nt = 0; nt < 8; nt++) {
        int n = nt * 16 + colc;
        float bias = b2[n];
        float sc = bnscale[n], sh = bnshift[n];
#pragma unroll
        for (int r = 0; r < 4; r++) {
            int row = m0 + wave * 16 + quad * 4 + r;
            if (row < N_NODES) {
                float z = acc2[nt][r] + bias;
                z = z * sc + sh;
                z = z > 0.f ? z : 0.f;
                __builtin_nontemporal_store(z, &h_out[row * DIM + n]);
                hb_out[row * DIM + n] = f2bf(z);
            }
        }
    }
}

// ---- launch --------------------------------------------------------------

extern "C" void kernel_launch(void* const* d_in, const int* in_sizes, int n_in,
                              void* d_out, int out_size, void* d_ws, size_t ws_size,
                              hipStream_t stream) {
    const float* x     = (const float*)d_in[0];
    const int* esrc    = (const int*)d_in[1];
    const int* edst    = (const int*)d_in[2];
    const float* eps   = (const float*)d_in[3];
    const float* W1    = (const float*)d_in[4];
    const float* b1    = (const float*)d_in[5];
    const float* W2    = (const float*)d_in[6];
    const float* b2    = (const float*)d_in[7];
    const float* gam   = (const float*)d_in[8];
    const float* bet   = (const float*)d_in[9];
    const float* bmean = (const float*)d_in[10];
    const float* bvar  = (const float*)d_in[11];
    float* out = (float*)d_out;

    char* ws = (char*)d_ws;
    unsigned short* hb0   = (unsigned short*)(ws);               // 12,800,000 B
    unsigned short* hb1   = (unsigned short*)(ws + 12800000);    // 12,800,000 B
    int*   col        = (int*)  (ws + 25600000);                 //  3,200,000 B
    int*   row_start  = (int*)  (ws + 28800000);                 //    200,004 B
    int*   cursor     = (int*)  (ws + 29000192);                 //    200,000 B
    int*   cnt        = (int*)  (ws + 29200384);                 //    200,000 B
    int*   blocksum   = (int*)  (ws + 29400576);                 //      1,024 B
    unsigned short* wpack = (unsigned short*)(ws + 29401600);    //    327,680 B
    float* bnscale    = (float*)(ws + 29729280);                 //      2,560 B
    float* bnshift    = (float*)(ws + 29731840);                 //      2,560 B
    unsigned short* pooled_b = (unsigned short*)(ws + 29734400); // 12,800,000 B

    init_zero_kernel<<<((N_NODES * DIM) / 4 + N_NODES + 255) / 256, 256, 0, stream>>>(
        x, out, hb0, cnt);
    hist_kernel<<<(N_EDGES + 255) / 256, 256, 0, stream>>>(edst, cnt);
    scanA_kernel<<<NBLK_SCAN, 256, 0, stream>>>(cnt, blocksum);
    scanB_kernel<<<1, 256, 0, stream>>>(blocksum, row_start);
    scanC_kernel<<<NBLK_SCAN, 256, 0, stream>>>(cnt, blocksum, row_start, cursor);
    fill_kernel<<<(N_EDGES + 255) / 256, 256, 0, stream>>>(esrc, edst, cursor, col);
    prep_kernel<<<(N_LAYERS * 2 * 2048 + N_LAYERS * DIM + 255) / 256, 256, 0, stream>>>(
        W1, W2, wpack, gam, bet, bmean, bvar, bnscale, bnshift);

    const int pool_blocks = (N_NODES + 3) / 4;   // 12500
    const int mlp_blocks  = (N_NODES + 63) / 64; // 782
    unsigned short* hbuf[2] = {hb0, hb1};
    for (int l = 0; l < N_LAYERS; l++) {
        float* h_next = out + (size_t)(l + 1) * N_NODES * DIM;
        pool_kernel<<<pool_blocks, 256, 0, stream>>>(hbuf[l & 1], row_start, col, eps + l,
                                                     pooled_b);
        mlp_kernel<<<mlp_blocks, 256, 0, stream>>>(
            pooled_b,
            wpack + (size_t)(l * 2) * 16384,
            wpack + (size_t)(l * 2 + 1) * 16384,
            b1 + l * DIM, b2 + l * DIM,
            bnscale + l * DIM, bnshift + l * DIM,
            h_next, hbuf[(l + 1) & 1]);
    }
}